// Round 8
// baseline (295.741 us; speedup 1.0000x reference)
//
#include <hip/hip_runtime.h>
#include <hip/hip_cooperative_groups.h>

namespace cg = cooperative_groups;

#define N_NODES 100000
#define N_EDGES 1000000
#define D 64
#define NCLS 10
#define NTILES (N_NODES / 16)   // 6250, exact

#define NBUCK 196            // buckets of 512 nodes: bucket = dst >> 9
#define BNODES 512
#define P_BLOCKS 256         // partition blocks (= cooperative grid size)
#define P_EPB 3907           // edges per partition block; 256*3907 >= 1M

#define CVT_BLOCKS (N_NODES * D / 4 / 256)   // 6250, exact

typedef __attribute__((ext_vector_type(8))) short bf16x8;   // 8 bf16 = 4 VGPR
typedef __attribute__((ext_vector_type(4))) float f32x4;

// round-to-nearest-even f32 -> bf16 bits
__device__ __forceinline__ unsigned short f2bf(float x) {
    unsigned int u = __float_as_uint(x);
    u += 0x7fffu + ((u >> 16) & 1u);
    return (unsigned short)(u >> 16);
}
__device__ __forceinline__ unsigned int pack2bf(float lo, float hi) {
    return (unsigned int)f2bf(lo) | ((unsigned int)f2bf(hi) << 16);
}
__device__ __forceinline__ float blo(unsigned int u) { return __uint_as_float(u << 16); }
__device__ __forceinline__ float bhi(unsigned int u) { return __uint_as_float(u & 0xffff0000u); }

// ---------------------------------------------------------------------------
// ONE cooperative kernel for the whole CSR build (replaces 6 kernels).
// 256 blocks (1/CU), 3 grid syncs. Edge record: (src<<9)|(dst&511).
// Phase 1: per-block LDS histogram + LDS-stage packed edges + write histG.
// Phase 2: blocks 0..195: exclusive row-prefix of histG[bk][*] -> ebase,
//          row totals -> scanP.
// Phase 3: all blocks: bucket offsets (scan of scanP, in LDS) + scatter
//          staged edges to bucket-sorted `pairs` (coalesced runs).
// Phase 4: blocks 0..195: per-bucket node hist + scan -> row_ptr, and
//          LDS-cursor scatter of src -> sorted_src.
// ---------------------------------------------------------------------------
__global__ __launch_bounds__(256) void csr_build(const int* __restrict__ src,
                                                 const int* __restrict__ dst,
                                                 int* __restrict__ histG,
                                                 int* __restrict__ scanP,
                                                 int* __restrict__ ebase,
                                                 unsigned int* __restrict__ pairs,
                                                 int* __restrict__ row_ptr,
                                                 int* __restrict__ sorted_src) {
    __shared__ unsigned int buf[P_EPB];   // staged packed edges (~15.6 KB)
    __shared__ int s[256];
    __shared__ int lbase[256];
    __shared__ int lcur[256];
    __shared__ int boff[NBUCK + 1];
    __shared__ int ebl[NBUCK];            // my block's ebase row cache
    __shared__ int h2[BNODES];            // phase-4 node histogram

    cg::grid_group grid = cg::this_grid();
    const int tid = threadIdx.x;
    const int blk = blockIdx.x;

    // ---- Phase 1 ----
    const int e0 = blk * P_EPB;
    int ecnt = N_EDGES - e0;
    if (ecnt > P_EPB) ecnt = P_EPB;
    if (ecnt < 0) ecnt = 0;

    lcur[tid] = 0;
    __syncthreads();
    for (int i = tid; i < ecnt; i += 256)
        atomicAdd(&lcur[dst[e0 + i] >> 9], 1);
    __syncthreads();
    int v = lcur[tid];
    s[tid] = v;
    __syncthreads();
    for (int st = 1; st < 256; st <<= 1) {
        int u = (tid >= st) ? s[tid - st] : 0;
        __syncthreads();
        s[tid] += u;
        __syncthreads();
    }
    int excl = s[tid] - v;
    lbase[tid] = excl;
    lcur[tid] = excl;
    if (tid < NBUCK) histG[tid * P_BLOCKS + blk] = v;
    __syncthreads();
    for (int i = tid; i < ecnt; i += 256) {
        int d = dst[e0 + i], sv = src[e0 + i];
        int p = atomicAdd(&lcur[d >> 9], 1);
        buf[p] = ((unsigned)sv << 9) | ((unsigned)d & 511u);
    }
    __threadfence();
    grid.sync();

    // ---- Phase 2 (blocks 0..195) ----
    if (blk < NBUCK) {
        int hv = histG[blk * P_BLOCKS + tid];
        s[tid] = hv;
        __syncthreads();
        for (int st = 1; st < 256; st <<= 1) {
            int u = (tid >= st) ? s[tid - st] : 0;
            __syncthreads();
            s[tid] += u;
            __syncthreads();
        }
        ebase[blk * P_BLOCKS + tid] = s[tid] - hv;
        if (tid == 255) scanP[blk] = s[255];
    }
    __threadfence();
    grid.sync();

    // ---- Phase 3 (all blocks) ----
    {
        int pv = (tid < NBUCK) ? scanP[tid] : 0;
        s[tid] = pv;
        __syncthreads();
        for (int st = 1; st < 256; st <<= 1) {
            int u = (tid >= st) ? s[tid - st] : 0;
            __syncthreads();
            s[tid] += u;
            __syncthreads();
        }
        if (tid < NBUCK) boff[tid] = s[tid] - pv;
        if (tid == 0) boff[NBUCK] = N_EDGES;
        if (tid < NBUCK) ebl[tid] = ebase[tid * P_BLOCKS + blk];
        __syncthreads();
        for (int i = tid; i < ecnt; i += 256) {
            unsigned int pr = buf[i];
            int lo = 0, hi = 255;        // last bk with lbase[bk] <= i
            while (lo < hi) {
                int mid = (lo + hi + 1) >> 1;
                if (lbase[mid] <= i) lo = mid; else hi = mid - 1;
            }
            int bk = lo;
            pairs[boff[bk] + ebl[bk] + (i - lbase[bk])] = pr;
        }
    }
    __threadfence();
    grid.sync();

    // ---- Phase 4 (blocks 0..195) ----
    if (blk < NBUCK) {
        const int base = boff[blk];
        const int next = boff[blk + 1];
        const int cnt = next - base;
        const int n0 = blk * BNODES;
        h2[tid] = 0; h2[tid + 256] = 0;
        __syncthreads();
        for (int i = tid; i < cnt; i += 256)
            atomicAdd(&h2[pairs[base + i] & 511u], 1);
        __syncthreads();
        int a0 = h2[2 * tid], a1 = h2[2 * tid + 1];
        s[tid] = a0 + a1;
        __syncthreads();
        for (int st = 1; st < 256; st <<= 1) {
            int u = (tid >= st) ? s[tid - st] : 0;
            __syncthreads();
            s[tid] += u;
            __syncthreads();
        }
        int eb = s[tid] - (a0 + a1);
        h2[2 * tid] = eb;
        h2[2 * tid + 1] = eb + a0;
        int node0 = n0 + 2 * tid;
        if (node0 <= N_NODES) row_ptr[node0] = base + eb;
        if (node0 + 1 <= N_NODES) row_ptr[node0 + 1] = base + eb + a0;
        __syncthreads();
        for (int i = tid; i < cnt; i += 256) {
            unsigned int pr = pairs[base + i];
            int p = atomicAdd(&h2[pr & 511u], 1);
            sorted_src[base + p] = (int)(pr >> 9);
        }
    }
}

// ---------------------------------------------------------------------------
// Fused prep kernel: bf16 feature table + all 3 weight packs (1 launch).
// Weight B-fragment layout: B = [Wl | Wr]^T as [K=128][64]. Frag (t,n):
// lane l: col j = n*16 + (l&15); k = t*32 + (l>>4)*8 + 2r(+1).
// ---------------------------------------------------------------------------
__global__ __launch_bounds__(256) void prep_all(const float* __restrict__ x,
                                                const float* __restrict__ W1l,
                                                const float* __restrict__ W1r,
                                                const float* __restrict__ W2l,
                                                const float* __restrict__ W2r,
                                                const float* __restrict__ Wout,
                                                unsigned short* __restrict__ xb,
                                                unsigned int* __restrict__ pB1,
                                                unsigned int* __restrict__ pB2,
                                                unsigned int* __restrict__ pBo) {
    const int b = blockIdx.x;
    const int tid = threadIdx.x;
    if (b < CVT_BLOCKS) {                       // x -> bf16 table
        int i = b * 256 + tid;                  // float4 index, exact bound
        float4 v = ((const float4*)x)[i];
        ushort4 o;
        o.x = f2bf(v.x); o.y = f2bf(v.y); o.z = f2bf(v.z); o.w = f2bf(v.w);
        ((ushort4*)xb)[i] = o;
    } else if (b < CVT_BLOCKS + 32) {           // two SAGE weight packs
        int wsel = (b - CVT_BLOCKS) >> 4;
        const float* Wl = wsel ? W2l : W1l;
        const float* Wr = wsel ? W2r : W1r;
        unsigned int* pB = wsel ? pB2 : pB1;
        int idx = ((b - CVT_BLOCKS) & 15) * 256 + tid;   // 0..4095
        int r    = idx & 3;
        int lane = (idx >> 2) & 63;
        int n    = (idx >> 8) & 3;
        int t    = idx >> 10;
        int j  = n * 16 + (lane & 15);
        int k0 = t * 32 + ((lane >> 4) << 3) + 2 * r;
        float lo = (k0 < 64) ? Wl[j * 64 + k0] : Wr[j * 64 + (k0 - 64)];
        float hi = (k0 + 1 < 64) ? Wl[j * 64 + k0 + 1] : Wr[j * 64 + (k0 - 63)];
        pB[idx] = pack2bf(lo, hi);
    } else {                                    // W_out pack (512 entries)
        int idx = (b - CVT_BLOCKS - 32) * 256 + tid;
        if (idx < 512) {
            int r    = idx & 3;
            int lane = (idx >> 2) & 63;
            int t    = idx >> 8;
            int j  = lane & 15;
            int k0 = t * 32 + ((lane >> 4) << 3) + 2 * r;
            float lo = (j < NCLS) ? Wout[j * 64 + k0] : 0.f;
            float hi = (j < NCLS) ? Wout[j * 64 + k0 + 1] : 0.f;
            pBo[idx] = pack2bf(lo, hi);
        }
    }
}

// ---------------------------------------------------------------------------
// Gather kernel: mean over CSR neighbors, bf16 rows -> bf16 mean rows.
// One wave per node; 8 lanes x dwordx4 per row => 8 EDGES PER WAVE-LOAD.
// Unroll 4 => one latency round covers 32 edges (deg<=32: single round).
// Index loads are broadcast per 8-lane group (no shfl in the address path).
// Zero LDS, ~45 VGPR -> 8 waves/SIMD.
// ---------------------------------------------------------------------------
__global__ __launch_bounds__(256) void gather_mean(
        const uint4* __restrict__ featb4,     // bf16 rows as [N][8] uint4
        const int* __restrict__ row_ptr,
        const int* __restrict__ sorted_src,
        uint4* __restrict__ meanb4) {         // bf16 mean rows [N][8] uint4
    const int l = threadIdx.x & 63;
    const int q = l & 7;        // row quarter (16B = feats 8q..8q+7)
    const int e = l >> 3;       // edge slot 0..7
    const int node = blockIdx.x * 4 + (threadIdx.x >> 6);   // grid exact

    const int start = row_ptr[node];
    const int end   = row_ptr[node + 1];
    const int deg   = end - start;

    float a0 = 0.f, a1 = 0.f, a2 = 0.f, a3 = 0.f,
          a4 = 0.f, a5 = 0.f, a6 = 0.f, a7 = 0.f;

    for (int base = 0; base < deg; base += 32) {
        const int i0 = start + base + e;
        int ei0 = i0, ei1 = i0 + 8, ei2 = i0 + 16, ei3 = i0 + 24;
        bool v0 = ei0 < end, v1 = ei1 < end, v2 = ei2 < end, v3 = ei3 < end;
        int s0 = sorted_src[v0 ? ei0 : start];
        int s1 = sorted_src[v1 ? ei1 : start];
        int s2 = sorted_src[v2 ? ei2 : start];
        int s3 = sorted_src[v3 ? ei3 : start];
        uint4 w0 = featb4[s0 * 8 + q];
        uint4 w1 = featb4[s1 * 8 + q];
        uint4 w2 = featb4[s2 * 8 + q];
        uint4 w3 = featb4[s3 * 8 + q];
        if (!v0) w0 = make_uint4(0, 0, 0, 0);
        if (!v1) w1 = make_uint4(0, 0, 0, 0);
        if (!v2) w2 = make_uint4(0, 0, 0, 0);
        if (!v3) w3 = make_uint4(0, 0, 0, 0);
        a0 += (blo(w0.x) + blo(w1.x)) + (blo(w2.x) + blo(w3.x));
        a1 += (bhi(w0.x) + bhi(w1.x)) + (bhi(w2.x) + bhi(w3.x));
        a2 += (blo(w0.y) + blo(w1.y)) + (blo(w2.y) + blo(w3.y));
        a3 += (bhi(w0.y) + bhi(w1.y)) + (bhi(w2.y) + bhi(w3.y));
        a4 += (blo(w0.z) + blo(w1.z)) + (blo(w2.z) + blo(w3.z));
        a5 += (bhi(w0.z) + bhi(w1.z)) + (bhi(w2.z) + bhi(w3.z));
        a6 += (blo(w0.w) + blo(w1.w)) + (blo(w2.w) + blo(w3.w));
        a7 += (bhi(w0.w) + bhi(w1.w)) + (bhi(w2.w) + bhi(w3.w));
    }

    // butterfly-reduce over the 8 edge slots (lane bits 3,4,5)
#pragma unroll
    for (int m = 8; m <= 32; m <<= 1) {
        a0 += __shfl_xor(a0, m); a1 += __shfl_xor(a1, m);
        a2 += __shfl_xor(a2, m); a3 += __shfl_xor(a3, m);
        a4 += __shfl_xor(a4, m); a5 += __shfl_xor(a5, m);
        a6 += __shfl_xor(a6, m); a7 += __shfl_xor(a7, m);
    }

    if (e == 0) {
        float inv = 1.0f / fmaxf((float)deg, 1.0f);
        uint4 o;
        o.x = pack2bf(a0 * inv, a1 * inv);
        o.y = pack2bf(a2 * inv, a3 * inv);
        o.z = pack2bf(a4 * inv, a5 * inv);
        o.w = pack2bf(a6 * inv, a7 * inv);
        meanb4[node * 8 + q] = o;   // 8 lanes x 16B = 128B coalesced
    }
}

// ---------------------------------------------------------------------------
// MFMA SAGE layer 1: outb = bf16(relu([mean||self] @ [Wl|Wr]^T + b))
// One 16-node tile per wave; zero LDS, no barriers.
// C/D: col = lane&15, row = (lane>>4)*4 + reg (m89).
// ---------------------------------------------------------------------------
__global__ __launch_bounds__(256) void sage_mfma(
        const unsigned int* __restrict__ selfb,    // bf16-packed [N][32]
        const unsigned int* __restrict__ meanb,    // bf16-packed [N][32]
        const unsigned int* __restrict__ packedB,  // 4096 dwords
        const float* __restrict__ bias,
        unsigned short* __restrict__ outb) {       // bf16 [N][64]
    const int wv = threadIdx.x >> 6;
    const int l  = threadIdx.x & 63;
    const int tile = blockIdx.x * 4 + wv;
    if (tile >= NTILES) return;
    const int col = l & 15;
    const int g   = l >> 4;
    const int anode = tile * 16 + col;

    bf16x8 bf[4][4];   // [K-tile][N-tile]
#pragma unroll
    for (int t = 0; t < 4; ++t)
#pragma unroll
        for (int n = 0; n < 4; ++n)
            bf[t][n] = *(const bf16x8*)(packedB + ((((t << 2) | n) * 64 + l) << 2));

    const unsigned int* mrow = meanb + anode * 32;
    const unsigned int* srw  = selfb + anode * 32;
    bf16x8 af0 = *(const bf16x8*)(mrow + (g << 2));        // K 0..31
    bf16x8 af1 = *(const bf16x8*)(mrow + 16 + (g << 2));   // K 32..63
    bf16x8 af2 = *(const bf16x8*)(srw + (g << 2));         // K 64..95
    bf16x8 af3 = *(const bf16x8*)(srw + 16 + (g << 2));    // K 96..127

    f32x4 acc[4];
#pragma unroll
    for (int n = 0; n < 4; ++n) {
        f32x4 a = {0.f, 0.f, 0.f, 0.f};
        a = __builtin_amdgcn_mfma_f32_16x16x32_bf16(af0, bf[0][n], a, 0, 0, 0);
        a = __builtin_amdgcn_mfma_f32_16x16x32_bf16(af1, bf[1][n], a, 0, 0, 0);
        a = __builtin_amdgcn_mfma_f32_16x16x32_bf16(af2, bf[2][n], a, 0, 0, 0);
        a = __builtin_amdgcn_mfma_f32_16x16x32_bf16(af3, bf[3][n], a, 0, 0, 0);
        acc[n] = a;
    }

#pragma unroll
    for (int n = 0; n < 4; ++n) {
        int j = (n << 4) | col;
        float bj = bias[j];
#pragma unroll
        for (int r = 0; r < 4; ++r) {
            int node = tile * 16 + (g << 2) + r;
            outb[node * 64 + j] = f2bf(fmaxf(acc[n][r] + bj, 0.f));
        }
    }
}

// ---------------------------------------------------------------------------
// MFMA SAGE layer 2 + FUSED output projection. The 16x64 h2 tile is complete
// in registers; bounce it through a wave-private LDS tile (stride-72 ushorts,
// 16B-aligned rows, max 2-way bank aliasing = free) into A-fragments and run
// the K=64 projection MFMAs. Eliminates out_mfma and the whole h2 buffer.
// ---------------------------------------------------------------------------
__global__ __launch_bounds__(256) void sage_mfma_out(
        const unsigned int* __restrict__ selfb,     // h1b bf16-packed [N][32]
        const unsigned int* __restrict__ meanb,
        const unsigned int* __restrict__ packedB,   // layer-2 weights
        const float* __restrict__ bias,             // b2
        const unsigned int* __restrict__ packedBo,  // 512 dwords
        const float* __restrict__ bout,
        float* __restrict__ out) {                  // fp32 [N][10]
    __shared__ __align__(16) unsigned short ht[4][16][72];
    const int wv = threadIdx.x >> 6;
    const int l  = threadIdx.x & 63;
    const int tile = blockIdx.x * 4 + wv;
    if (tile >= NTILES) return;     // no barriers below -> early return safe
    const int col = l & 15;
    const int g   = l >> 4;
    const int anode = tile * 16 + col;

    bf16x8 bf[4][4];
#pragma unroll
    for (int t = 0; t < 4; ++t)
#pragma unroll
        for (int n = 0; n < 4; ++n)
            bf[t][n] = *(const bf16x8*)(packedB + ((((t << 2) | n) * 64 + l) << 2));

    const unsigned int* mrow = meanb + anode * 32;
    const unsigned int* srw  = selfb + anode * 32;
    bf16x8 af0 = *(const bf16x8*)(mrow + (g << 2));
    bf16x8 af1 = *(const bf16x8*)(mrow + 16 + (g << 2));
    bf16x8 af2 = *(const bf16x8*)(srw + (g << 2));
    bf16x8 af3 = *(const bf16x8*)(srw + 16 + (g << 2));

    f32x4 acc[4];
#pragma unroll
    for (int n = 0; n < 4; ++n) {
        f32x4 a = {0.f, 0.f, 0.f, 0.f};
        a = __builtin_amdgcn_mfma_f32_16x16x32_bf16(af0, bf[0][n], a, 0, 0, 0);
        a = __builtin_amdgcn_mfma_f32_16x16x32_bf16(af1, bf[1][n], a, 0, 0, 0);
        a = __builtin_amdgcn_mfma_f32_16x16x32_bf16(af2, bf[2][n], a, 0, 0, 0);
        a = __builtin_amdgcn_mfma_f32_16x16x32_bf16(af3, bf[3][n], a, 0, 0, 0);
        acc[n] = a;
    }

    // epilogue: bias+relu -> bf16 into wave-private LDS tile [node][feat]
#pragma unroll
    for (int n = 0; n < 4; ++n) {
        float bj = bias[(n << 4) | col];
#pragma unroll
        for (int r = 0; r < 4; ++r)
            ht[wv][(g << 2) + r][(n << 4) | col] = f2bf(fmaxf(acc[n][r] + bj, 0.f));
    }
    asm volatile("" ::: "memory");          // keep ds_writes ordered before reads
    __builtin_amdgcn_sched_barrier(0);

    // projection: A = h2 tile (row = node = lane&15, k = feat), K=64
    bf16x8 bo0 = *(const bf16x8*)(packedBo + (l << 2));
    bf16x8 bo1 = *(const bf16x8*)(packedBo + ((64 + l) << 2));
    bf16x8 ha0 = *(const bf16x8*)&ht[wv][col][g << 3];        // feats 0..31 slice
    bf16x8 ha1 = *(const bf16x8*)&ht[wv][col][32 + (g << 3)]; // feats 32..63 slice

    f32x4 acc2 = {0.f, 0.f, 0.f, 0.f};
    acc2 = __builtin_amdgcn_mfma_f32_16x16x32_bf16(ha0, bo0, acc2, 0, 0, 0);
    acc2 = __builtin_amdgcn_mfma_f32_16x16x32_bf16(ha1, bo1, acc2, 0, 0, 0);

    if (col < NCLS) {
        float bj = bout[col];
#pragma unroll
        for (int r = 0; r < 4; ++r)
            out[(tile * 16 + (g << 2) + r) * NCLS + col] = acc2[r] + bj;
    }
}

// ---------------------------------------------------------------------------
extern "C" void kernel_launch(void* const* d_in, const int* in_sizes, int n_in,
                              void* d_out, int out_size, void* d_ws, size_t ws_size,
                              hipStream_t stream) {
    const float* x   = (const float*)d_in[0];
    const int*   ei  = (const int*)d_in[1];   // [2, N_EDGES]
    const float* W1l = (const float*)d_in[2];
    const float* W1r = (const float*)d_in[3];
    const float* b1  = (const float*)d_in[4];
    const float* W2l = (const float*)d_in[5];
    const float* W2r = (const float*)d_in[6];
    const float* b2  = (const float*)d_in[7];
    const float* Wo  = (const float*)d_in[8];
    const float* bo  = (const float*)d_in[9];
    float* out = (float*)d_out;

    char* ws = (char*)d_ws;
    int*   histG      = (int*)(ws + 0x0000000);  // 50176 ints
    int*   scanP      = (int*)(ws + 0x0040000);  // 196 ints
    int*   ebase      = (int*)(ws + 0x0044000);  // 50176 ints
    int*   row_ptr    = (int*)(ws + 0x0080000);  // 100001 ints
    unsigned int* pairs = (unsigned int*)(ws + 0x0100000);     // 4 MB (packed)
    int*   sorted_src = (int*)(ws + 0x0500000);                // 4 MB
    unsigned short* xb    = (unsigned short*)(ws + 0x0900000); // 12.8 MB bf16
    unsigned int*   meanb = (unsigned int*)(ws + 0x1540000);   // 12.8 MB bf16
    unsigned short* h1b   = (unsigned short*)(ws + 0x2180000); // 12.8 MB bf16
    unsigned int* packedB1 = (unsigned int*)(ws + 0x2DC0000);  // 16 KB
    unsigned int* packedB2 = (unsigned int*)(ws + 0x2DC4000);  // 16 KB
    unsigned int* packedBo = (unsigned int*)(ws + 0x2DC8000);  // 2 KB

    const int gather_blocks = N_NODES / 4;             // 25000, exact
    const int mfma_blocks   = (NTILES + 3) / 4;        // 1563
    const int prep_blocks   = CVT_BLOCKS + 32 + 2;     // 6284

    // ---- CSR build: ONE cooperative kernel (3 grid syncs) ----
    const int* srcp = ei;
    const int* dstp = ei + N_EDGES;
    void* cargs[] = {(void*)&srcp, (void*)&dstp, (void*)&histG, (void*)&scanP,
                     (void*)&ebase, (void*)&pairs, (void*)&row_ptr, (void*)&sorted_src};
    hipLaunchCooperativeKernel((const void*)csr_build, dim3(P_BLOCKS), dim3(256),
                               cargs, 0, stream);

    // ---- fused prep: bf16 table + weight packs (1 launch) ----
    prep_all<<<prep_blocks, 256, 0, stream>>>(x, W1l, W1r, W2l, W2r, Wo,
                                              xb, packedB1, packedB2, packedBo);

    // ---- layer 1 ----
    gather_mean<<<gather_blocks, 256, 0, stream>>>((const uint4*)xb,
                                                   row_ptr, sorted_src,
                                                   (uint4*)meanb);
    sage_mfma<<<mfma_blocks, 256, 0, stream>>>((const unsigned int*)xb, meanb,
                                               packedB1, b1, h1b);

    // ---- layer 2 + fused output projection ----
    gather_mean<<<gather_blocks, 256, 0, stream>>>((const uint4*)h1b,
                                                   row_ptr, sorted_src,
                                                   (uint4*)meanb);
    sage_mfma_out<<<mfma_blocks, 256, 0, stream>>>((const unsigned int*)h1b, meanb,
                                                   packedB2, b2, packedBo, bo, out);
}

// Round 9
// 134.032 us; speedup vs baseline: 2.2065x; 2.2065x over previous
//
#include <hip/hip_runtime.h>

#define N_NODES 100000
#define N_EDGES 1000000
#define D 64
#define NCLS 10
#define NTILES (N_NODES / 16)   // 6250, exact

#define NBUCK 196            // buckets of 512 nodes: bucket = dst >> 9
#define BNODES 512
#define P_BLOCKS 256         // partition blocks
#define P_EPB 3907           // edges per partition block; 256*3907 >= 1M

#define CVT_BLOCKS (N_NODES * D / 4 / 256)   // 6250, exact

typedef __attribute__((ext_vector_type(8))) short bf16x8;   // 8 bf16 = 4 VGPR
typedef __attribute__((ext_vector_type(4))) float f32x4;

// round-to-nearest-even f32 -> bf16 bits
__device__ __forceinline__ unsigned short f2bf(float x) {
    unsigned int u = __float_as_uint(x);
    u += 0x7fffu + ((u >> 16) & 1u);
    return (unsigned short)(u >> 16);
}
__device__ __forceinline__ unsigned int pack2bf(float lo, float hi) {
    return (unsigned int)f2bf(lo) | ((unsigned int)f2bf(hi) << 16);
}
__device__ __forceinline__ float blo(unsigned int u) { return __uint_as_float(u << 16); }
__device__ __forceinline__ float bhi(unsigned int u) { return __uint_as_float(u & 0xffff0000u); }

// ---------------------------------------------------------------------------
// Kernel 1 (merged): blocks 0..255 -> per-(block,bucket) edge histogram;
// blocks 256.. -> prep (bf16 feature table + 3 weight packs). Independent
// work merged to cut a dispatch and overlap latency- with BW-bound phases.
// ---------------------------------------------------------------------------
__global__ __launch_bounds__(256) void hist_prep(const int* __restrict__ dst,
                                                 int* __restrict__ histG,
                                                 const float* __restrict__ x,
                                                 const float* __restrict__ W1l,
                                                 const float* __restrict__ W1r,
                                                 const float* __restrict__ W2l,
                                                 const float* __restrict__ W2r,
                                                 const float* __restrict__ Wout,
                                                 unsigned short* __restrict__ xb,
                                                 unsigned int* __restrict__ pB1,
                                                 unsigned int* __restrict__ pB2,
                                                 unsigned int* __restrict__ pBo) {
    const int tid = threadIdx.x;
    if (blockIdx.x < P_BLOCKS) {                 // ---- edge histogram ----
        __shared__ int lh[256];
        lh[tid] = 0;
        __syncthreads();
        const int e0 = blockIdx.x * P_EPB;
        int ecnt = N_EDGES - e0;
        if (ecnt > P_EPB) ecnt = P_EPB;
        if (ecnt < 0) ecnt = 0;
        for (int i = tid; i < ecnt; i += 256)
            atomicAdd(&lh[dst[e0 + i] >> 9], 1);   // LDS atomic
        __syncthreads();
        if (tid < NBUCK) histG[tid * P_BLOCKS + blockIdx.x] = lh[tid];
        return;
    }
    const int b = blockIdx.x - P_BLOCKS;
    if (b < CVT_BLOCKS) {                        // ---- x -> bf16 table ----
        int i = b * 256 + tid;                   // float4 index, exact bound
        float4 v = ((const float4*)x)[i];
        ushort4 o;
        o.x = f2bf(v.x); o.y = f2bf(v.y); o.z = f2bf(v.z); o.w = f2bf(v.w);
        ((ushort4*)xb)[i] = o;
    } else if (b < CVT_BLOCKS + 32) {            // ---- SAGE weight packs ----
        int wsel = (b - CVT_BLOCKS) >> 4;
        const float* Wl = wsel ? W2l : W1l;
        const float* Wr = wsel ? W2r : W1r;
        unsigned int* pB = wsel ? pB2 : pB1;
        int idx = ((b - CVT_BLOCKS) & 15) * 256 + tid;   // 0..4095
        int r    = idx & 3;
        int lane = (idx >> 2) & 63;
        int n    = (idx >> 8) & 3;
        int t    = idx >> 10;
        int j  = n * 16 + (lane & 15);
        int k0 = t * 32 + ((lane >> 4) << 3) + 2 * r;
        float lo = (k0 < 64) ? Wl[j * 64 + k0] : Wr[j * 64 + (k0 - 64)];
        float hi = (k0 + 1 < 64) ? Wl[j * 64 + k0 + 1] : Wr[j * 64 + (k0 - 63)];
        pB[idx] = pack2bf(lo, hi);
    } else {                                     // ---- W_out pack ----
        int idx = (b - CVT_BLOCKS - 32) * 256 + tid;
        if (idx < 512) {
            int r    = idx & 3;
            int lane = (idx >> 2) & 63;
            int t    = idx >> 8;
            int j  = lane & 15;
            int k0 = t * 32 + ((lane >> 4) << 3) + 2 * r;
            float lo = (j < NCLS) ? Wout[j * 64 + k0] : 0.f;
            float hi = (j < NCLS) ? Wout[j * 64 + k0 + 1] : 0.f;
            pBo[idx] = pack2bf(lo, hi);
        }
    }
}

// ---------------------------------------------------------------------------
// Kernel 2: per-256-chunk sums of histG rows (196 blocks).
// ---------------------------------------------------------------------------
__global__ __launch_bounds__(256) void scan_partials(const int* __restrict__ in,
                                                     int* __restrict__ blockSum) {
    __shared__ int s[256];
    s[threadIdx.x] = in[blockIdx.x * 256 + threadIdx.x];
    __syncthreads();
    for (int st = 128; st > 0; st >>= 1) {
        if (threadIdx.x < st) s[threadIdx.x] += s[threadIdx.x + st];
        __syncthreads();
    }
    if (threadIdx.x == 0) blockSum[blockIdx.x] = s[0];
}

// ---------------------------------------------------------------------------
// Kernel 3: full exclusive scan -> ebase. Each block re-scans the 196 row
// totals in LDS (cheap) to get its own offset -- folds the former
// scan_offsets kernel away.
// ---------------------------------------------------------------------------
__global__ __launch_bounds__(256) void scan_final(const int* __restrict__ in,
                                                  const int* __restrict__ blockSum,
                                                  int* __restrict__ ebase) {
    __shared__ int p[256];
    __shared__ int s[256];
    const int t = threadIdx.x;
    // scan the 196 row totals
    int pv = (t < NBUCK) ? blockSum[t] : 0;
    p[t] = pv;
    __syncthreads();
    for (int st = 1; st < 256; st <<= 1) {
        int u = (t >= st) ? p[t - st] : 0;
        __syncthreads();
        p[t] += u;
        __syncthreads();
    }
    const int rowOff = (blockIdx.x > 0) ? p[blockIdx.x - 1] : 0;
    // scan own chunk
    const int i = blockIdx.x * 256 + t;
    int v = in[i];
    s[t] = v;
    __syncthreads();
    for (int st = 1; st < 256; st <<= 1) {
        int u = (t >= st) ? s[t - st] : 0;
        __syncthreads();
        s[t] += u;
        __syncthreads();
    }
    ebase[i] = s[t] - v + rowOff;
}

// ---------------------------------------------------------------------------
// Kernel 4: partition edges into bucket-sorted packed array. Full (src,dst)
// staged in LDS (uint2, 31KB) so the scatter computes its bucket directly --
// no binary search. Packed record: (src<<9)|(dst&511).
// ---------------------------------------------------------------------------
__global__ __launch_bounds__(256) void edge_partition(const int* __restrict__ src,
                                                      const int* __restrict__ dst,
                                                      const int* __restrict__ ebase,
                                                      unsigned int* __restrict__ pairs) {
    __shared__ int s[256];
    __shared__ int lbase[256];
    __shared__ int lcur[256];
    __shared__ uint2 buf[P_EPB];     // 31.2 KB
    const int tid = threadIdx.x;
    const int e0 = blockIdx.x * P_EPB;
    int ecnt = N_EDGES - e0;
    if (ecnt > P_EPB) ecnt = P_EPB;
    if (ecnt < 0) ecnt = 0;

    lcur[tid] = 0;
    __syncthreads();
    for (int i = tid; i < ecnt; i += 256)
        atomicAdd(&lcur[dst[e0 + i] >> 9], 1);
    __syncthreads();
    int v = lcur[tid];
    s[tid] = v;
    __syncthreads();
    for (int st = 1; st < 256; st <<= 1) {
        int u = (tid >= st) ? s[tid - st] : 0;
        __syncthreads();
        s[tid] += u;
        __syncthreads();
    }
    int excl = s[tid] - v;
    lbase[tid] = excl;
    lcur[tid] = excl;
    __syncthreads();
    for (int i = tid; i < ecnt; i += 256) {
        int d = dst[e0 + i], sv = src[e0 + i];
        int p = atomicAdd(&lcur[d >> 9], 1);
        buf[p] = make_uint2((unsigned)sv, (unsigned)d);
    }
    __syncthreads();
    for (int i = tid; i < ecnt; i += 256) {
        uint2 pr = buf[i];
        int bk = (int)(pr.y >> 9);
        pairs[ebase[bk * P_BLOCKS + blockIdx.x] + (i - lbase[bk])] =
            (pr.x << 9) | (pr.y & 511u);
    }
}

// ---------------------------------------------------------------------------
// Kernel 5: per-bucket node hist + scan -> row_ptr; LDS-cursor scatter of
// src into sorted_src. One block owns one contiguous output region.
// ---------------------------------------------------------------------------
__global__ __launch_bounds__(256) void bucket_csr(const unsigned int* __restrict__ pairs,
                                                  const int* __restrict__ ebase,
                                                  int* __restrict__ row_ptr,
                                                  int* __restrict__ sorted_src) {
    __shared__ int h[BNODES];    // counts -> exclusive scan -> cursors
    __shared__ int part[256];
    const int tid = threadIdx.x;
    const int b = blockIdx.x;
    const int base = ebase[b * P_BLOCKS];
    const int next = (b == NBUCK - 1) ? N_EDGES : ebase[(b + 1) * P_BLOCKS];
    const int cnt = next - base;
    const int n0 = b * BNODES;

    h[tid] = 0; h[tid + 256] = 0;
    __syncthreads();
    for (int i = tid; i < cnt; i += 256)
        atomicAdd(&h[pairs[base + i] & 511u], 1);
    __syncthreads();
    int a0 = h[2 * tid], a1 = h[2 * tid + 1];
    part[tid] = a0 + a1;
    __syncthreads();
    for (int st = 1; st < 256; st <<= 1) {
        int u = (tid >= st) ? part[tid - st] : 0;
        __syncthreads();
        part[tid] += u;
        __syncthreads();
    }
    int eb = part[tid] - (a0 + a1);          // exclusive base of node pair
    h[2 * tid] = eb;
    h[2 * tid + 1] = eb + a0;
    int node0 = n0 + 2 * tid;
    if (node0 <= N_NODES) row_ptr[node0] = base + eb;
    if (node0 + 1 <= N_NODES) row_ptr[node0 + 1] = base + eb + a0;
    __syncthreads();
    for (int i = tid; i < cnt; i += 256) {
        unsigned int pr = pairs[base + i];
        int p = atomicAdd(&h[pr & 511u], 1);
        sorted_src[base + p] = (int)(pr >> 9);
    }
}

// ---------------------------------------------------------------------------
// Gather kernel: mean over CSR neighbors, bf16 rows -> bf16 mean rows.
// One wave per node; 8 lanes x dwordx4 per row => 8 EDGES PER WAVE-LOAD.
// Unroll 4 => one latency round covers 32 edges (deg<=32: single round).
// Zero LDS, low VGPR -> 8 waves/SIMD.
// ---------------------------------------------------------------------------
__global__ __launch_bounds__(256) void gather_mean(
        const uint4* __restrict__ featb4,     // bf16 rows as [N][8] uint4
        const int* __restrict__ row_ptr,
        const int* __restrict__ sorted_src,
        uint4* __restrict__ meanb4) {         // bf16 mean rows [N][8] uint4
    const int l = threadIdx.x & 63;
    const int q = l & 7;        // row quarter (16B = feats 8q..8q+7)
    const int e = l >> 3;       // edge slot 0..7
    const int node = blockIdx.x * 4 + (threadIdx.x >> 6);   // grid exact

    const int start = row_ptr[node];
    const int end   = row_ptr[node + 1];
    const int deg   = end - start;

    float a0 = 0.f, a1 = 0.f, a2 = 0.f, a3 = 0.f,
          a4 = 0.f, a5 = 0.f, a6 = 0.f, a7 = 0.f;

    for (int base = 0; base < deg; base += 32) {
        const int i0 = start + base + e;
        int ei0 = i0, ei1 = i0 + 8, ei2 = i0 + 16, ei3 = i0 + 24;
        bool v0 = ei0 < end, v1 = ei1 < end, v2 = ei2 < end, v3 = ei3 < end;
        int s0 = sorted_src[v0 ? ei0 : start];
        int s1 = sorted_src[v1 ? ei1 : start];
        int s2 = sorted_src[v2 ? ei2 : start];
        int s3 = sorted_src[v3 ? ei3 : start];
        uint4 w0 = featb4[s0 * 8 + q];
        uint4 w1 = featb4[s1 * 8 + q];
        uint4 w2 = featb4[s2 * 8 + q];
        uint4 w3 = featb4[s3 * 8 + q];
        if (!v0) w0 = make_uint4(0, 0, 0, 0);
        if (!v1) w1 = make_uint4(0, 0, 0, 0);
        if (!v2) w2 = make_uint4(0, 0, 0, 0);
        if (!v3) w3 = make_uint4(0, 0, 0, 0);
        a0 += (blo(w0.x) + blo(w1.x)) + (blo(w2.x) + blo(w3.x));
        a1 += (bhi(w0.x) + bhi(w1.x)) + (bhi(w2.x) + bhi(w3.x));
        a2 += (blo(w0.y) + blo(w1.y)) + (blo(w2.y) + blo(w3.y));
        a3 += (bhi(w0.y) + bhi(w1.y)) + (bhi(w2.y) + bhi(w3.y));
        a4 += (blo(w0.z) + blo(w1.z)) + (blo(w2.z) + blo(w3.z));
        a5 += (bhi(w0.z) + bhi(w1.z)) + (bhi(w2.z) + bhi(w3.z));
        a6 += (blo(w0.w) + blo(w1.w)) + (blo(w2.w) + blo(w3.w));
        a7 += (bhi(w0.w) + bhi(w1.w)) + (bhi(w2.w) + bhi(w3.w));
    }

    // butterfly-reduce over the 8 edge slots (lane bits 3,4,5)
#pragma unroll
    for (int m = 8; m <= 32; m <<= 1) {
        a0 += __shfl_xor(a0, m); a1 += __shfl_xor(a1, m);
        a2 += __shfl_xor(a2, m); a3 += __shfl_xor(a3, m);
        a4 += __shfl_xor(a4, m); a5 += __shfl_xor(a5, m);
        a6 += __shfl_xor(a6, m); a7 += __shfl_xor(a7, m);
    }

    if (e == 0) {
        float inv = 1.0f / fmaxf((float)deg, 1.0f);
        uint4 o;
        o.x = pack2bf(a0 * inv, a1 * inv);
        o.y = pack2bf(a2 * inv, a3 * inv);
        o.z = pack2bf(a4 * inv, a5 * inv);
        o.w = pack2bf(a6 * inv, a7 * inv);
        meanb4[node * 8 + q] = o;   // 8 lanes x 16B = 128B coalesced
    }
}

// ---------------------------------------------------------------------------
// MFMA SAGE layer 1: outb = bf16(relu([mean||self] @ [Wl|Wr]^T + b))
// One 16-node tile per wave; zero LDS, no barriers.
// C/D: col = lane&15, row = (lane>>4)*4 + reg (m89).
// ---------------------------------------------------------------------------
__global__ __launch_bounds__(256) void sage_mfma(
        const unsigned int* __restrict__ selfb,    // bf16-packed [N][32]
        const unsigned int* __restrict__ meanb,    // bf16-packed [N][32]
        const unsigned int* __restrict__ packedB,  // 4096 dwords
        const float* __restrict__ bias,
        unsigned short* __restrict__ outb) {       // bf16 [N][64]
    const int wv = threadIdx.x >> 6;
    const int l  = threadIdx.x & 63;
    const int tile = blockIdx.x * 4 + wv;
    if (tile >= NTILES) return;
    const int col = l & 15;
    const int g   = l >> 4;
    const int anode = tile * 16 + col;

    bf16x8 bf[4][4];   // [K-tile][N-tile]
#pragma unroll
    for (int t = 0; t < 4; ++t)
#pragma unroll
        for (int n = 0; n < 4; ++n)
            bf[t][n] = *(const bf16x8*)(packedB + ((((t << 2) | n) * 64 + l) << 2));

    const unsigned int* mrow = meanb + anode * 32;
    const unsigned int* srw  = selfb + anode * 32;
    bf16x8 af0 = *(const bf16x8*)(mrow + (g << 2));        // K 0..31
    bf16x8 af1 = *(const bf16x8*)(mrow + 16 + (g << 2));   // K 32..63
    bf16x8 af2 = *(const bf16x8*)(srw + (g << 2));         // K 64..95
    bf16x8 af3 = *(const bf16x8*)(srw + 16 + (g << 2));    // K 96..127

    f32x4 acc[4];
#pragma unroll
    for (int n = 0; n < 4; ++n) {
        f32x4 a = {0.f, 0.f, 0.f, 0.f};
        a = __builtin_amdgcn_mfma_f32_16x16x32_bf16(af0, bf[0][n], a, 0, 0, 0);
        a = __builtin_amdgcn_mfma_f32_16x16x32_bf16(af1, bf[1][n], a, 0, 0, 0);
        a = __builtin_amdgcn_mfma_f32_16x16x32_bf16(af2, bf[2][n], a, 0, 0, 0);
        a = __builtin_amdgcn_mfma_f32_16x16x32_bf16(af3, bf[3][n], a, 0, 0, 0);
        acc[n] = a;
    }

#pragma unroll
    for (int n = 0; n < 4; ++n) {
        int j = (n << 4) | col;
        float bj = bias[j];
#pragma unroll
        for (int r = 0; r < 4; ++r) {
            int node = tile * 16 + (g << 2) + r;
            outb[node * 64 + j] = f2bf(fmaxf(acc[n][r] + bj, 0.f));
        }
    }
}

// ---------------------------------------------------------------------------
// MFMA SAGE layer 2 + FUSED output projection (verified in round 8). The
// 16x64 h2 tile bounces through a wave-private LDS tile (stride-72 ushorts,
// max 2-way bank aliasing = free) into A-fragments for the K=64 projection.
// Eliminates out_mfma and the whole h2 buffer.
// ---------------------------------------------------------------------------
__global__ __launch_bounds__(256) void sage_mfma_out(
        const unsigned int* __restrict__ selfb,     // h1b bf16-packed [N][32]
        const unsigned int* __restrict__ meanb,
        const unsigned int* __restrict__ packedB,   // layer-2 weights
        const float* __restrict__ bias,             // b2
        const unsigned int* __restrict__ packedBo,  // 512 dwords
        const float* __restrict__ bout,
        float* __restrict__ out) {                  // fp32 [N][10]
    __shared__ __align__(16) unsigned short ht[4][16][72];
    const int wv = threadIdx.x >> 6;
    const int l  = threadIdx.x & 63;
    const int tile = blockIdx.x * 4 + wv;
    if (tile >= NTILES) return;     // no barriers below -> early return safe
    const int col = l & 15;
    const int g   = l >> 4;
    const int anode = tile * 16 + col;

    bf16x8 bf[4][4];
#pragma unroll
    for (int t = 0; t < 4; ++t)
#pragma unroll
        for (int n = 0; n < 4; ++n)
            bf[t][n] = *(const bf16x8*)(packedB + ((((t << 2) | n) * 64 + l) << 2));

    const unsigned int* mrow = meanb + anode * 32;
    const unsigned int* srw  = selfb + anode * 32;
    bf16x8 af0 = *(const bf16x8*)(mrow + (g << 2));
    bf16x8 af1 = *(const bf16x8*)(mrow + 16 + (g << 2));
    bf16x8 af2 = *(const bf16x8*)(srw + (g << 2));
    bf16x8 af3 = *(const bf16x8*)(srw + 16 + (g << 2));

    f32x4 acc[4];
#pragma unroll
    for (int n = 0; n < 4; ++n) {
        f32x4 a = {0.f, 0.f, 0.f, 0.f};
        a = __builtin_amdgcn_mfma_f32_16x16x32_bf16(af0, bf[0][n], a, 0, 0, 0);
        a = __builtin_amdgcn_mfma_f32_16x16x32_bf16(af1, bf[1][n], a, 0, 0, 0);
        a = __builtin_amdgcn_mfma_f32_16x16x32_bf16(af2, bf[2][n], a, 0, 0, 0);
        a = __builtin_amdgcn_mfma_f32_16x16x32_bf16(af3, bf[3][n], a, 0, 0, 0);
        acc[n] = a;
    }

    // epilogue: bias+relu -> bf16 into wave-private LDS tile [node][feat]
#pragma unroll
    for (int n = 0; n < 4; ++n) {
        float bj = bias[(n << 4) | col];
#pragma unroll
        for (int r = 0; r < 4; ++r)
            ht[wv][(g << 2) + r][(n << 4) | col] = f2bf(fmaxf(acc[n][r] + bj, 0.f));
    }
    asm volatile("" ::: "memory");          // keep ds_writes ordered before reads
    __builtin_amdgcn_sched_barrier(0);

    // projection: A = h2 tile (row = node = lane&15, k = feat), K=64
    bf16x8 bo0 = *(const bf16x8*)(packedBo + (l << 2));
    bf16x8 bo1 = *(const bf16x8*)(packedBo + ((64 + l) << 2));
    bf16x8 ha0 = *(const bf16x8*)&ht[wv][col][g << 3];        // feats 0..31 slice
    bf16x8 ha1 = *(const bf16x8*)&ht[wv][col][32 + (g << 3)]; // feats 32..63 slice

    f32x4 acc2 = {0.f, 0.f, 0.f, 0.f};
    acc2 = __builtin_amdgcn_mfma_f32_16x16x32_bf16(ha0, bo0, acc2, 0, 0, 0);
    acc2 = __builtin_amdgcn_mfma_f32_16x16x32_bf16(ha1, bo1, acc2, 0, 0, 0);

    if (col < NCLS) {
        float bj = bout[col];
#pragma unroll
        for (int r = 0; r < 4; ++r)
            out[(tile * 16 + (g << 2) + r) * NCLS + col] = acc2[r] + bj;
    }
}

// ---------------------------------------------------------------------------
extern "C" void kernel_launch(void* const* d_in, const int* in_sizes, int n_in,
                              void* d_out, int out_size, void* d_ws, size_t ws_size,
                              hipStream_t stream) {
    const float* x   = (const float*)d_in[0];
    const int*   ei  = (const int*)d_in[1];   // [2, N_EDGES]
    const int*   src = ei;
    const int*   dst = ei + N_EDGES;
    const float* W1l = (const float*)d_in[2];
    const float* W1r = (const float*)d_in[3];
    const float* b1  = (const float*)d_in[4];
    const float* W2l = (const float*)d_in[5];
    const float* W2r = (const float*)d_in[6];
    const float* b2  = (const float*)d_in[7];
    const float* Wo  = (const float*)d_in[8];
    const float* bo  = (const float*)d_in[9];
    float* out = (float*)d_out;

    char* ws = (char*)d_ws;
    int*   histG      = (int*)(ws + 0x0000000);  // 50176 ints
    int*   scanP      = (int*)(ws + 0x0040000);  // 196 ints
    int*   ebase      = (int*)(ws + 0x0044000);  // 50176 ints
    int*   row_ptr    = (int*)(ws + 0x0080000);  // 100001 ints
    unsigned int* pairs = (unsigned int*)(ws + 0x0100000);     // 4 MB (packed)
    int*   sorted_src = (int*)(ws + 0x0500000);                // 4 MB
    unsigned short* xb    = (unsigned short*)(ws + 0x0900000); // 12.8 MB bf16
    unsigned int*   meanb = (unsigned int*)(ws + 0x1540000);   // 12.8 MB bf16
    unsigned short* h1b   = (unsigned short*)(ws + 0x2180000); // 12.8 MB bf16
    unsigned int* packedB1 = (unsigned int*)(ws + 0x2DC0000);  // 16 KB
    unsigned int* packedB2 = (unsigned int*)(ws + 0x2DC4000);  // 16 KB
    unsigned int* packedBo = (unsigned int*)(ws + 0x2DC8000);  // 2 KB

    const int gather_blocks = N_NODES / 4;             // 25000, exact
    const int mfma_blocks   = (NTILES + 3) / 4;        // 1563
    const int hp_blocks     = P_BLOCKS + CVT_BLOCKS + 32 + 2;  // 6540

    // ---- CSR build (5 dispatches, no cooperative launch) ----
    hist_prep<<<hp_blocks, 256, 0, stream>>>(dst, histG, x, W1l, W1r, W2l, W2r,
                                             Wo, xb, packedB1, packedB2, packedBo);
    scan_partials<<<NBUCK, 256, 0, stream>>>(histG, scanP);
    scan_final<<<NBUCK, 256, 0, stream>>>(histG, scanP, ebase);
    edge_partition<<<P_BLOCKS, 256, 0, stream>>>(src, dst, ebase, pairs);
    bucket_csr<<<NBUCK, 256, 0, stream>>>(pairs, ebase, row_ptr, sorted_src);

    // ---- layer 1 ----
    gather_mean<<<gather_blocks, 256, 0, stream>>>((const uint4*)xb,
                                                   row_ptr, sorted_src,
                                                   (uint4*)meanb);
    sage_mfma<<<mfma_blocks, 256, 0, stream>>>((const unsigned int*)xb, meanb,
                                               packedB1, b1, h1b);

    // ---- layer 2 + fused output projection ----
    gather_mean<<<gather_blocks, 256, 0, stream>>>((const uint4*)h1b,
                                                   row_ptr, sorted_src,
                                                   (uint4*)meanb);
    sage_mfma_out<<<mfma_blocks, 256, 0, stream>>>((const unsigned int*)h1b, meanb,
                                                   packedB2, b2, packedBo, bo, out);
}